// Round 10
// baseline (126.144 us; speedup 1.0000x reference)
//
#include <hip/hip_runtime.h>

// Sinkhorn (dustbin-augmented), MFMA edition v10.
//
// Scaled exp-domain state (A = 2^{alpha*log2e}, Cs = 2^8/A):
//   EU_i  = 1/(sum_j es_ij*EV_j + A*evd)         es = 2^{s*log2e} (f16)
//   eud_s = Cs/(sum_j EV_j + evd)
//   EV_j  = 1/(sum_i es_ij*EU_i + A*eud_s)
//   evd'  = Cs/(sum_i EU_i + eud_s)
//   Z core = (log2 es + log2 EU + log2 EV)*ln2   (dustbins use alpha2)
//
// v9 -> v10: (1) Sum(EV)/Sum(EU) are computed from the SAME fragment
// registers the MFMAs consume (pk_add_f16 tree + xor16/xor32 fold), removing
// the wsU/wsV LDS round-trip + serial 16-sum from the critical path;
// (2) epilogue writes from esA fragments + a fresh EV-fragment read (esT is
// prologue-only now -- its 8-way-conflicted epilogue reads were the bulk of
// v9's 4.7M conflict cycles); (3) MFMA chains split 4-way (dep depth 2).
//
// Fragment maps (proven v8/v9): wave w, lane l = l15 + 16g:
//   esA[s][j] = es[16w+l15][s*32+g*8+j]   (A operand, row strip)
//   esB[s][j] = es[s*32+g*8+j][16w+l15]   (B operand, col strip)
//   EV/EU fragment chunk s reads elements [(s*4+g)*8 .. +8)
// C/D layout: col=lane&15, row=(lane>>4)*4+reg (HW-measured).

typedef _Float16 half8 __attribute__((ext_vector_type(8)));
typedef float floatx4 __attribute__((ext_vector_type(4)));

constexpr float L2E = 1.4426950408889634f;
constexpr float LN2 = 0.6931471805599453f;

__device__ __forceinline__ float flog2(float x) { return __builtin_amdgcn_logf(x); }
__device__ __forceinline__ float fexp2(float x) { return __builtin_amdgcn_exp2f(x); }

// 1/d via v_rcp_f32 + one Newton step (<=1 ulp, d>0)
__device__ __forceinline__ float rcp_nr(float d) {
    float r = __builtin_amdgcn_rcpf(d);
    return r * fmaf(-d, r, 2.0f);
}

__device__ __forceinline__ float xor16_add(float x) {
    int y = __builtin_amdgcn_ds_swizzle(__builtin_bit_cast(int, x), 0x401F);
    return x + __builtin_bit_cast(float, y);
}
// fold per-g partials (lanes l, l^16, l^32, l^48 hold g=0..3) -> wave-uniform
__device__ __forceinline__ float gsum(float x) {
    x = xor16_add(x);
    x += __shfl_xor(x, 32, 64);
    return x;
}
// horizontal sum of 8 f16 chunks (pk_add tree, then f32 horizontal)
__device__ __forceinline__ float fragsum(const half8* f) {
    half8 a = (f[0] + f[1]) + (f[2] + f[3]);
    half8 b = (f[4] + f[5]) + (f[6] + f[7]);
    half8 c = a + b;   // elements are sums of 8 originals
    return (((float)c[0] + (float)c[1]) + ((float)c[2] + (float)c[3]))
         + (((float)c[4] + (float)c[5]) + ((float)c[6] + (float)c[7]));
}

__global__ __launch_bounds__(1024)
__attribute__((amdgpu_waves_per_eu(4, 4)))
void sinkhorn_kernel(const float* __restrict__ scores,
                     const float* __restrict__ alpha_p,
                     const int* __restrict__ iters_p,
                     float* __restrict__ out)
{
    const int bat = blockIdx.x;
    const int t   = threadIdx.x;
    const int a   = t >> 5;         // prologue: rows [8a, 8a+8)
    const int bb  = t & 31;         // prologue: cols 4bb.. / 128+4bb..
    const int w   = t >> 6;         // wave 0..15
    const int l   = t & 63;
    const int g   = (t >> 4) & 3;   // k-group within wave
    const int l15 = t & 15;

    const float alpha2 = alpha_p[0] * L2E;
    const float A  = fexp2(alpha2);
    const float Cs = fexp2(8.0f - alpha2);   // 2^8 / A
    const int iters = iters_p[0];

    __shared__ __align__(16) unsigned short esT[65536];  // 128 KB (prologue staging)
    __shared__ __align__(16) unsigned short EUa[272];
    __shared__ __align__(16) unsigned short EVa[272];

    // ---------------- prologue: load scores -> f16 es^T (swizzled) ----------------
    {
        const float* sp = scores + ((size_t)bat << 16) + ((size_t)a << 11) + (bb << 2);
        half8 cp[8];  // per-column packs of this thread's 8 rows
        #pragma unroll
        for (int r = 0; r < 8; ++r) {
            const float4 x0 = *reinterpret_cast<const float4*>(sp + (r << 8));
            const float4 x1 = *reinterpret_cast<const float4*>(sp + (r << 8) + 128);
            cp[0][r] = (_Float16)fexp2(x0.x * L2E);
            cp[1][r] = (_Float16)fexp2(x0.y * L2E);
            cp[2][r] = (_Float16)fexp2(x0.z * L2E);
            cp[3][r] = (_Float16)fexp2(x0.w * L2E);
            cp[4][r] = (_Float16)fexp2(x1.x * L2E);
            cp[5][r] = (_Float16)fexp2(x1.y * L2E);
            cp[6][r] = (_Float16)fexp2(x1.z * L2E);
            cp[7][r] = (_Float16)fexp2(x1.w * L2E);
        }
        #pragma unroll
        for (int ci = 0; ci < 8; ++ci) {
            const int col = (ci < 4) ? ((bb << 2) + ci) : (128 + (bb << 2) + ci - 4);
            const int idx = (col << 8) + (((a << 3)) ^ ((col & 7) << 3));
            *reinterpret_cast<half8*>(&esT[idx]) = cp[ci];
        }
    }
    if (t < 256) EVa[t] = 0x3C00;      // EV = 1.0 (f16)
    __syncthreads();

    // ---- persistent A-fragments: es row strip of wave w (asm-pinned) ----
    half8 esA[8];
    {
        const int m16 = (w << 4) + l15;
        #pragma unroll
        for (int s = 0; s < 8; ++s) {
            #pragma unroll
            for (int j = 0; j < 8; ++j) {
                const int col = (s << 5) + (g << 3) + j;
                const unsigned short v =
                    esT[(col << 8) + (m16 ^ ((col & 7) << 3))];
                esA[s][j] = __builtin_bit_cast(_Float16, v);
            }
            asm volatile("" : "+v"(esA[s]));  // opaque def: no remat
        }
    }
    // ---- persistent B-fragments: es col strip ----
    half8 esB[8];
    {
        const int cbase = ((w << 4) + l15) << 8;
        const int swq = (l15 & 7) << 3;
        #pragma unroll
        for (int s = 0; s < 8; ++s) {
            esB[s] = *reinterpret_cast<const half8*>(
                &esT[cbase + (((s << 5) + (g << 3)) ^ swq)]);
            asm volatile("" : "+v"(esB[s]));  // opaque def: no remat
        }
    }

    float evd = 1.0f, eud_s = 1.0f;
    float tdv = A;  // A * evd

    const half8* evp = reinterpret_cast<const half8*>(EVa) + g;
    const half8* eup = reinterpret_cast<const half8*>(EUa) + g;

    for (int it = 0; it < iters; ++it) {
        // ---------------- p-phase: EU from EV ----------------
        half8 evf[8];
        #pragma unroll
        for (int s = 0; s < 8; ++s) evf[s] = evp[s << 2];

        floatx4 ac[4];
        #pragma unroll
        for (int k = 0; k < 4; ++k) ac[k] = (floatx4){0.f, 0.f, 0.f, 0.f};
        #pragma unroll
        for (int s = 0; s < 8; ++s)
            ac[s & 3] = __builtin_amdgcn_mfma_f32_16x16x32_f16(esA[s], evf[s], ac[s & 3], 0, 0, 0);
        const floatx4 acc = (ac[0] + ac[1]) + (ac[2] + ac[3]);

        // Sum(EV) from the same fragments (overlaps the MFMA chain)
        const float sv = gsum(fragsum(evf));
        eud_s = Cs * rcp_nr(sv + evd);
        const float tdu = A * eud_s;

        const float E0 = rcp_nr(acc[0] + tdv);
        const float E1 = rcp_nr(acc[1] + tdv);
        const float E2 = rcp_nr(acc[2] + tdv);
        const float E3 = rcp_nr(acc[3] + tdv);
        if (l15 < 4) {  // rows 16w + 4g + l15
            const float lo  = (l15 & 1) ? E1 : E0;
            const float hi  = (l15 & 1) ? E3 : E2;
            const float val = (l15 & 2) ? hi : lo;
            EUa[(w << 4) + (g << 2) + l15] =
                __builtin_bit_cast(unsigned short, (_Float16)val);
        }
        __syncthreads();

        // ---------------- q-phase: EV from EU ----------------
        half8 euf[8];
        #pragma unroll
        for (int s = 0; s < 8; ++s) euf[s] = eup[s << 2];

        floatx4 qc[4];
        #pragma unroll
        for (int k = 0; k < 4; ++k) qc[k] = (floatx4){0.f, 0.f, 0.f, 0.f};
        #pragma unroll
        for (int s = 0; s < 8; ++s)
            qc[s & 3] = __builtin_amdgcn_mfma_f32_16x16x32_f16(euf[s], esB[s], qc[s & 3], 0, 0, 0);
        const floatx4 acc2 = (qc[0] + qc[1]) + (qc[2] + qc[3]);

        // Sum(EU) from the same fragments
        const float su = gsum(fragsum(euf));
        evd = Cs * rcp_nr(su + eud_s);
        tdv = A * evd;

        const float EVv = rcp_nr(acc2[0] + tdu);   // col 16w+l15 (rows replicated)
        if (l < 16) EVa[(w << 4) + l] =
            __builtin_bit_cast(unsigned short, (_Float16)EVv);
        __syncthreads();
    }

    // ---------------- epilogue (from fragments; esT not touched) ----------------
    half8 evf[8];
    #pragma unroll
    for (int s = 0; s < 8; ++s) evf[s] = evp[s << 2];

    const float Ud = flog2(eud_s);
    const float Vd = flog2(evd);
    const float Up_l = flog2((float)__builtin_bit_cast(_Float16, EUa[(w << 4) + l15]));
    const int row = (w << 4) + l15;
    const size_t ob = (size_t)bat * 66049;  // 257*257
    float* rp = out + ob + (size_t)row * 257;

    #pragma unroll
    for (int s = 0; s < 8; ++s) {
        const int c0 = (s << 5) + (g << 3);
        #pragma unroll
        for (int j = 0; j < 8; ++j) {
            rp[c0 + j] = (flog2((float)esA[s][j]) + Up_l + flog2((float)evf[s][j])) * LN2;
        }
    }
    if (l < 16) rp[256] = (alpha2 + Up_l + Vd) * LN2;   // dustbin column
    // dustbin row (i=256), incl. corner at j=256
    if (t < 257) {
        const float vp = (t < 256)
            ? flog2((float)__builtin_bit_cast(_Float16, EVa[t])) : Vd;
        out[ob + 65792 + t] = (alpha2 + Ud + vp) * LN2;
    }
}

extern "C" void kernel_launch(void* const* d_in, const int* in_sizes, int n_in,
                              void* d_out, int out_size, void* d_ws, size_t ws_size,
                              hipStream_t stream)
{
    const float* scores = (const float*)d_in[0];
    const float* alpha  = (const float*)d_in[1];
    const int*   iters  = (const int*)d_in[2];
    float* out = (float*)d_out;
    const int B = in_sizes[0] >> 16;
    hipLaunchKernelGGL(sinkhorn_kernel, dim3(B), dim3(1024), 0, stream,
                       scores, alpha, iters, out);
}

// Round 11
// 109.680 us; speedup vs baseline: 1.1501x; 1.1501x over previous
//
#include <hip/hip_runtime.h>

// Sinkhorn (dustbin-augmented), MFMA edition v11 = v9 loop + v10 epilogue.
//
// Scaled exp-domain state (A = 2^{alpha*log2e}, Cs = 2^8/A):
//   EU_i  = 1/(sum_j es_ij*EV_j + A*evd)         es = 2^{s*log2e} (f16)
//   eud_s = Cs/(sum_j EV_j + evd)
//   EV_j  = 1/(sum_i es_ij*EU_i + A*eud_s)
//   evd'  = Cs/(sum_i EU_i + eud_s)
//   Z core = (log2 es + log2 EU + log2 EV)*ln2   (dustbins use alpha2)
//
// v9 loop (103 us, fastest): wsU/wsV scalar round-trip overlaps the MFMA
// chain fine; EV/EU fragments are read from LDS inside the MFMA loop
// (broadcast reads, no extra live ranges). v10's fragment-upfront loop
// REGRESSED (126 us: +32 live regs over a full register file) -- reverted.
// v10 epilogue (verified correct): output written from esA fragments + one
// EVa fragment read; esT is prologue-only, killing its 8-way-conflicted
// epilogue reads (conflicts 4.7M -> 2.9M measured).
//
// Fragment maps (proven v8/v9/v10): wave w, lane l = l15 + 16g:
//   esA[s][j] = es[16w+l15][s*32+g*8+j]   (A operand, row strip)
//   esB[s][j] = es[s*32+g*8+j][16w+l15]   (B operand, col strip)
//   EV/EU fragment chunk s reads elements [(s*4+g)*8 .. +8)
// C/D layout: col=lane&15, row=(lane>>4)*4+reg (HW-measured).

typedef _Float16 half8 __attribute__((ext_vector_type(8)));
typedef float floatx4 __attribute__((ext_vector_type(4)));

constexpr float L2E = 1.4426950408889634f;
constexpr float LN2 = 0.6931471805599453f;

__device__ __forceinline__ float flog2(float x) { return __builtin_amdgcn_logf(x); }
__device__ __forceinline__ float fexp2(float x) { return __builtin_amdgcn_exp2f(x); }

// 1/d via v_rcp_f32 + one Newton step (<=1 ulp, d>0)
__device__ __forceinline__ float rcp_nr(float d) {
    float r = __builtin_amdgcn_rcpf(d);
    return r * fmaf(-d, r, 2.0f);
}

template <int CTRL>
__device__ __forceinline__ float dpp_add(float x) {
    int y = __builtin_amdgcn_update_dpp(0, __builtin_bit_cast(int, x), CTRL, 0xF, 0xF, true);
    return x + __builtin_bit_cast(float, y);
}
// sum over the 16 lanes of each row (lanes l&15)
__device__ __forceinline__ float reduce16(float x) {
    x = dpp_add<0xB1>(x);    // xor 1
    x = dpp_add<0x4E>(x);    // xor 2
    x = dpp_add<0x124>(x);   // row_ror:4
    x = dpp_add<0x128>(x);   // row_ror:8
    return x;
}
__device__ __forceinline__ float xor16_add(float x) {
    int y = __builtin_amdgcn_ds_swizzle(__builtin_bit_cast(int, x), 0x401F);
    return x + __builtin_bit_cast(float, y);
}

__global__ __launch_bounds__(1024)
__attribute__((amdgpu_waves_per_eu(4, 4)))
void sinkhorn_kernel(const float* __restrict__ scores,
                     const float* __restrict__ alpha_p,
                     const int* __restrict__ iters_p,
                     float* __restrict__ out)
{
    const int bat = blockIdx.x;
    const int t   = threadIdx.x;
    const int a   = t >> 5;         // prologue: rows [8a, 8a+8)
    const int bb  = t & 31;         // prologue: cols 4bb.. / 128+4bb..
    const int w   = t >> 6;         // wave 0..15
    const int l   = t & 63;
    const int g   = (t >> 4) & 3;   // k-group within wave
    const int l15 = t & 15;

    const float alpha2 = alpha_p[0] * L2E;
    const float A  = fexp2(alpha2);
    const float Cs = fexp2(8.0f - alpha2);   // 2^8 / A
    const int iters = iters_p[0];

    __shared__ __align__(16) unsigned short esT[65536];  // 128 KB (prologue staging)
    __shared__ __align__(16) unsigned short EUa[272];
    __shared__ __align__(16) unsigned short EVa[272];
    __shared__ __align__(16) float wsU[16];
    __shared__ __align__(16) float wsV[16];

    // ---------------- prologue: load scores -> f16 es^T (swizzled) ----------------
    {
        const float* sp = scores + ((size_t)bat << 16) + ((size_t)a << 11) + (bb << 2);
        half8 cp[8];  // per-column packs of this thread's 8 rows
        #pragma unroll
        for (int r = 0; r < 8; ++r) {
            const float4 x0 = *reinterpret_cast<const float4*>(sp + (r << 8));
            const float4 x1 = *reinterpret_cast<const float4*>(sp + (r << 8) + 128);
            cp[0][r] = (_Float16)fexp2(x0.x * L2E);
            cp[1][r] = (_Float16)fexp2(x0.y * L2E);
            cp[2][r] = (_Float16)fexp2(x0.z * L2E);
            cp[3][r] = (_Float16)fexp2(x0.w * L2E);
            cp[4][r] = (_Float16)fexp2(x1.x * L2E);
            cp[5][r] = (_Float16)fexp2(x1.y * L2E);
            cp[6][r] = (_Float16)fexp2(x1.z * L2E);
            cp[7][r] = (_Float16)fexp2(x1.w * L2E);
        }
        #pragma unroll
        for (int ci = 0; ci < 8; ++ci) {
            const int col = (ci < 4) ? ((bb << 2) + ci) : (128 + (bb << 2) + ci - 4);
            const int idx = (col << 8) + (((a << 3)) ^ ((col & 7) << 3));
            *reinterpret_cast<half8*>(&esT[idx]) = cp[ci];
        }
    }
    if (t < 256) EVa[t] = 0x3C00;      // EV = 1.0 (f16)
    if (t < 16)  wsV[t] = 16.0f;       // per-wave sum of 16 ones
    __syncthreads();

    // ---- persistent A-fragments: es row strip of wave w (asm-pinned) ----
    half8 esA[8];
    {
        const int m16 = (w << 4) + l15;
        #pragma unroll
        for (int s = 0; s < 8; ++s) {
            #pragma unroll
            for (int j = 0; j < 8; ++j) {
                const int col = (s << 5) + (g << 3) + j;
                const unsigned short v =
                    esT[(col << 8) + (m16 ^ ((col & 7) << 3))];
                esA[s][j] = __builtin_bit_cast(_Float16, v);
            }
            asm volatile("" : "+v"(esA[s]));  // opaque def: no remat
        }
    }
    // ---- persistent B-fragments: es col strip ----
    half8 esB[8];
    {
        const int cbase = ((w << 4) + l15) << 8;
        const int swq = (l15 & 7) << 3;
        #pragma unroll
        for (int s = 0; s < 8; ++s) {
            esB[s] = *reinterpret_cast<const half8*>(
                &esT[cbase + (((s << 5) + (g << 3)) ^ swq)]);
            asm volatile("" : "+v"(esB[s]));  // opaque def: no remat
        }
    }

    float evd = 1.0f, eud_s = 1.0f;

    const half8* evp = reinterpret_cast<const half8*>(EVa) + g;
    const half8* eup = reinterpret_cast<const half8*>(EUa) + g;

    for (int it = 0; it < iters; ++it) {
        // ---- scalars: eud_s from Sum(EV) + evd (all threads, redundant) ----
        float sv = evd;
        {
            const floatx4* wv = reinterpret_cast<const floatx4*>(wsV);
            floatx4 s0 = wv[0], s1 = wv[1], s2 = wv[2], s3 = wv[3];
            floatx4 ss = (s0 + s1) + (s2 + s3);
            sv += (ss[0] + ss[1]) + (ss[2] + ss[3]);
        }
        eud_s = Cs * rcp_nr(sv);
        const float tdu = A * eud_s;
        const float tdv = A * evd;

        // ---- p-phase: D[m][*] = sum_k es[m][k]*EV[k] (2x4 indep chains) ----
        floatx4 acc0 = {0.f, 0.f, 0.f, 0.f}, acc1 = {0.f, 0.f, 0.f, 0.f};
        #pragma unroll
        for (int s = 0; s < 4; ++s) {
            acc0 = __builtin_amdgcn_mfma_f32_16x16x32_f16(esA[2*s],   evp[(2*s) << 2],   acc0, 0, 0, 0);
            acc1 = __builtin_amdgcn_mfma_f32_16x16x32_f16(esA[2*s+1], evp[(2*s+1) << 2], acc1, 0, 0, 0);
        }
        floatx4 acc = acc0 + acc1;

        const float E0 = rcp_nr(acc[0] + tdv);
        const float E1 = rcp_nr(acc[1] + tdv);
        const float E2 = rcp_nr(acc[2] + tdv);
        const float E3 = rcp_nr(acc[3] + tdv);
        if (l15 < 4) {  // rows 16w + 4g + l15
            const float lo  = (l15 & 1) ? E1 : E0;
            const float hi  = (l15 & 1) ? E3 : E2;
            const float val = (l15 & 2) ? hi : lo;
            EUa[(w << 4) + (g << 2) + l15] =
                __builtin_bit_cast(unsigned short, (_Float16)val);
        }
        float sU = (E0 + E1) + (E2 + E3);
        sU = xor16_add(sU);
        sU += __shfl_xor(sU, 32, 64);
        if (l == 0) wsU[w] = sU;
        __syncthreads();

        // ---- scalars: evd' from Sum(EU) + eud_s ----
        float su = eud_s;
        {
            const floatx4* wu = reinterpret_cast<const floatx4*>(wsU);
            floatx4 s0 = wu[0], s1 = wu[1], s2 = wu[2], s3 = wu[3];
            floatx4 ss = (s0 + s1) + (s2 + s3);
            su += (ss[0] + ss[1]) + (ss[2] + ss[3]);
        }
        evd = Cs * rcp_nr(su);

        // ---- q-phase: D[*][n] = sum_k EU[k]*es[k][n] (2x4 indep chains) ----
        floatx4 q0 = {0.f, 0.f, 0.f, 0.f}, q1 = {0.f, 0.f, 0.f, 0.f};
        #pragma unroll
        for (int s = 0; s < 4; ++s) {
            q0 = __builtin_amdgcn_mfma_f32_16x16x32_f16(eup[(2*s) << 2],   esB[2*s],   q0, 0, 0, 0);
            q1 = __builtin_amdgcn_mfma_f32_16x16x32_f16(eup[(2*s+1) << 2], esB[2*s+1], q1, 0, 0, 0);
        }
        floatx4 acc2 = q0 + q1;

        const float EVv = rcp_nr(acc2[0] + tdu);   // col 16w+l15 (rows replicated)
        if (l < 16) EVa[(w << 4) + l] =
            __builtin_bit_cast(unsigned short, (_Float16)EVv);
        float sV = reduce16(EVv);
        if (l == 0) wsV[w] = sV;
        __syncthreads();
    }

    // ------- epilogue (v10-verified: from fragments; esT not touched) -------
    half8 evf[8];
    #pragma unroll
    for (int s = 0; s < 8; ++s) evf[s] = evp[s << 2];

    const float Ud = flog2(eud_s);
    const float Vd = flog2(evd);
    const float Up_l = flog2((float)__builtin_bit_cast(_Float16, EUa[(w << 4) + l15]));
    const int row = (w << 4) + l15;
    const size_t ob = (size_t)bat * 66049;  // 257*257
    float* rp = out + ob + (size_t)row * 257;

    #pragma unroll
    for (int s = 0; s < 8; ++s) {
        const int c0 = (s << 5) + (g << 3);
        #pragma unroll
        for (int j = 0; j < 8; ++j) {
            rp[c0 + j] = (flog2((float)esA[s][j]) + Up_l + flog2((float)evf[s][j])) * LN2;
        }
    }
    if (l < 16) rp[256] = (alpha2 + Up_l + Vd) * LN2;   // dustbin column
    // dustbin row (i=256), incl. corner at j=256
    if (t < 257) {
        const float vp = (t < 256)
            ? flog2((float)__builtin_bit_cast(_Float16, EVa[t])) : Vd;
        out[ob + 65792 + t] = (alpha2 + Ud + vp) * LN2;
    }
}

extern "C" void kernel_launch(void* const* d_in, const int* in_sizes, int n_in,
                              void* d_out, int out_size, void* d_ws, size_t ws_size,
                              hipStream_t stream)
{
    const float* scores = (const float*)d_in[0];
    const float* alpha  = (const float*)d_in[1];
    const int*   iters  = (const int*)d_in[2];
    float* out = (float*)d_out;
    const int B = in_sizes[0] >> 16;
    hipLaunchKernelGGL(sinkhorn_kernel, dim3(B), dim3(1024), 0, stream,
                       scores, alpha, iters, out);
}